// Round 9
// baseline (89.290 us; speedup 1.0000x reference)
//
#include <hip/hip_runtime.h>
#include <cstdint>
#include <cstddef>

// Problem constants
#define NB 2
#define NF 8
#define NS 4
#define NK 90      // real K (dirs per shell)
#define NP 642     // grid vertices
#define NXYZ 1728  // 12*12*12
#define MT 64      // p-tile
#define PTILES 11  // ceil(642/64)
#define NG 108     // xyz 16-groups (1728/16)
#define XSEG 192   // xyz per gemm block (1728 = 9*192)
#define GSEG 12    // 16-groups per segment
#define NSEG 9
#define XT_TASKS (64 * NG * 3)          // 20736 x-fragment blocks (1 KB each)
#define WT_TASKS (NS * PTILES * 4 * 3)  // 528 W-fragment blocks
#define LROW 768   // LDS row bytes (192 * 4)

typedef __attribute__((ext_vector_type(8))) __bf16 bf16x8;
typedef __attribute__((ext_vector_type(4))) float f32x4;
typedef __attribute__((ext_vector_type(4))) uint32_t u32x4;

// RNE pack of two f32 -> u32 holding 2 bf16
__device__ __forceinline__ uint32_t pack2bf(float a, float b) {
    uint32_t ua = __builtin_bit_cast(uint32_t, a);
    uint32_t ub = __builtin_bit_cast(uint32_t, b);
    ua += 0x7FFFu + ((ua >> 16) & 1u);
    ub += 0x7FFFu + ((ub >> 16) & 1u);
    return (ua >> 16) | (ub & 0xFFFF0000u);
}

// ============ Kernel 1: pack x and W into MFMA-fragment-order bf16 blocks.
// (unchanged since R5 — layout proven.)
__global__ __launch_bounds__(256) void prep_frag(
    const float* __restrict__ x, const float* __restrict__ Wm,
    uint32_t* __restrict__ ws)
{
    const int tid  = (int)threadIdx.x;
    const int lane = tid & 63;
    const int lr = lane & 15, lg = lane >> 4;
    const int task = (int)blockIdx.x * 4 + (tid >> 6);

    float v[8];
    if (task < XT_TASKS) {
        int t = task;
        const int kk = t % 3;   t /= 3;
        const int g  = t % NG;  t /= NG;
        const int e  = t;                  // 0..63
        const int s = e & 3, bf = e >> 2;
        const float* src = x + (size_t)bf * (NS * NK * NXYZ)
                             + (size_t)s * (NK * NXYZ) + g * 16 + lr;
        #pragma unroll
        for (int j = 0; j < 8; ++j) {
            const int k = kk * 32 + lg * 8 + j;
            v[j] = (k < NK) ? src[(size_t)k * NXYZ] : 0.f;
        }
    } else {
        int t = task - XT_TASKS;
        const int kk = t % 3;      t /= 3;
        const int ni = t % 4;      t /= 4;
        const int pt = t % PTILES; t /= PTILES;
        const int s  = t;                  // 0..3
        const int p = pt * MT + ni * 16 + lr;
        const float* src = Wm + (size_t)s * (NK * NP) + p;
        #pragma unroll
        for (int j = 0; j < 8; ++j) {
            const int k = kk * 32 + lg * 8 + j;
            v[j] = (k < NK && p < NP) ? src[(size_t)k * NP] : 0.f;
        }
    }
    u32x4 u;
    u.x = pack2bf(v[0], v[1]);
    u.y = pack2bf(v[2], v[3]);
    u.z = pack2bf(v[4], v[5]);
    u.w = pack2bf(v[6], v[7]);
    *(u32x4*)((char*)ws + (size_t)task * 1024 + lane * 16) = u;
}

// ============ Kernel 2: frag-GEMM with LDS-transpose epilogue.
// Block (256 thr, 4 waves) = one (e, seg, sub): 64 p x 192 xyz tile.
// Compute into 48 KB LDS [p64][xyz192] f32 (swizzled ^((p&7)<<4), slot-
// uniform -> minimum-cycle b128), one barrier, then store the tile in
// ascending-address order: ~1 KB contiguous per instruction, 64 dense
// consecutive rows per block -> DRAM page-hit writeback stream.
__global__ __launch_bounds__(256, 3) void gemm_t(
    const uint32_t* __restrict__ ws, float* __restrict__ y)
{
    __shared__ __align__(16) char tile[MT * LROW];  // 48 KB

    const int tid  = (int)threadIdx.x;
    const int lane = tid & 63;
    const int w    = tid >> 6;          // wave 0..3
    const int lr = lane & 15, lg = lane >> 4;

    int t = (int)blockIdx.x;
    const int sub = t % PTILES; t /= PTILES;  // sub fastest: siblings share x_t
    const int seg = t % NSEG;   t /= NSEG;
    const int e   = t;                         // 0..63
    const int s = e & 3, bfi = e >> 2;
    const int b = bfi >> 3, f = bfi & 7;

    const char* lbase = (const char*)ws + (size_t)lane * 16;

    // A-frags for this 64-p tile: 4 nj x 3 kk (1 KB each), L2-hot.
    const char* ab = lbase
        + ((size_t)XT_TASKS + (size_t)((s * PTILES + sub) * 4) * 3) * 1024;
    bf16x8 A[4][3];
    #pragma unroll
    for (int nj = 0; nj < 4; ++nj)
        #pragma unroll
        for (int kk = 0; kk < 3; ++kk)
            A[nj][kk] = *(const bf16x8*)(ab + (nj * 3 + kk) * 1024);

    // Compute: wave w owns 16-groups g_l = w*3..w*3+2 (48 xyz columns).
    const int swz = (lr & 7) << 4;   // p_l & 7 == lr & 7 for all nj
    #pragma unroll
    for (int gi = 0; gi < 3; ++gi) {
        const int g_l = w * 3 + gi;            // 0..11 within segment
        const int g   = seg * GSEG + g_l;      // global 16-group
        const char* xb = lbase + (size_t)((e * NG + g) * 3) * 1024;
        bf16x8 B0 = *(const bf16x8*)(xb);
        bf16x8 B1 = *(const bf16x8*)(xb + 1024);
        bf16x8 B2 = *(const bf16x8*)(xb + 2048);
        #pragma unroll
        for (int nj = 0; nj < 4; ++nj) {
            f32x4 acc = (f32x4){0.f, 0.f, 0.f, 0.f};
            acc = __builtin_amdgcn_mfma_f32_16x16x32_bf16(B0, A[nj][0], acc, 0, 0, 0);
            acc = __builtin_amdgcn_mfma_f32_16x16x32_bf16(B1, A[nj][1], acc, 0, 0, 0);
            acc = __builtin_amdgcn_mfma_f32_16x16x32_bf16(B2, A[nj][2], acc, 0, 0, 0);
            // D[xyz = lg*4 + r][p = lr]: lane's 4 floats = consecutive xyz.
            const int byte = (nj * 16 + lr) * LROW + g_l * 64 + lg * 16;
            *(f32x4*)(tile + (byte ^ swz)) = acc;
        }
    }

    __syncthreads();  // the ONLY barrier

    // Store: tile in ascending address order. fq -> (p_l = fq/48, xq = fq%48);
    // per instruction 64 consecutive 16 B chunks -> ~1 KB contiguous segments.
    const size_t chan = (size_t)b * (NS * NF) + (size_t)s * NF + f;
    float* ybase = y + chan * ((size_t)NP * NXYZ) + seg * XSEG;
    const int p0 = sub * MT;
    #pragma unroll
    for (int pass = 0; pass < 12; ++pass) {
        const int fq  = tid + pass * 256;
        const int p_l = fq / 48;
        const int xq  = fq - p_l * 48;
        const f32x4 v = *(const f32x4*)(
            tile + ((p_l * LROW + xq * 16) ^ ((p_l & 7) << 4)));
        const int p = p0 + p_l;
        if (p < NP)
            *(f32x4*)(ybase + (size_t)p * NXYZ + xq * 4) = v;
    }
}

// ============ Fallback (round-3 structure) if ws too small ================
#define NT 96
#define NTILES 18
#define KP 96
#define ROWB (KP * 2)

__global__ __launch_bounds__(192, 4) void interp_fallback(
    const float* __restrict__ x, const float* __restrict__ Wm,
    float* __restrict__ y)
{
    __shared__ __align__(16) char As[MT * ROWB];
    __shared__ __align__(16) char Bs[NT * ROWB];

    int blk = (int)blockIdx.x;
    const int nt = blk % NTILES; blk /= NTILES;
    const int f  = blk % NF;     blk /= NF;
    const int s  = blk % NS;     blk /= NS;
    const int b  = blk;
    const int tid = (int)threadIdx.x;
    const int n0 = nt * NT;

    {
        const int c  = tid % NT;
        const int kh = tid / NT;
        const float* xp = x + (((size_t)b * NF + f) * (NS * NK) + (size_t)s * NK) * NXYZ
                            + n0 + c;
        const int cs = (c & 7) << 4;
        #pragma unroll
        for (int kk = 0; kk < 48; kk += 8) {
            const int kb = kh * 48 + kk;
            float v[8];
            #pragma unroll
            for (int j = 0; j < 8; ++j) {
                const int k = kb + j;
                v[j] = (k < NK) ? xp[(size_t)k * NXYZ] : 0.f;
            }
            u32x4 u;
            u.x = pack2bf(v[0], v[1]); u.y = pack2bf(v[2], v[3]);
            u.z = pack2bf(v[4], v[5]); u.w = pack2bf(v[6], v[7]);
            *(u32x4*)(Bs + ((c * ROWB + kb * 2) ^ cs)) = u;
        }
    }

    const int lane = tid & 63;
    const int w  = tid / 64;
    const int lr = lane & 15;
    const int lg = lane >> 4;
    const int ls = (lr & 7) << 4;
    const size_t chan = (size_t)b * (NS * NF) + (size_t)s * NF + f;
    float* ybase = y + chan * ((size_t)NP * NXYZ);
    const int xyzbase = n0 + w * 32 + lg * 4;
    const int ar = tid & 63;
    const int akc = tid >> 6;
    const int ars = (ar & 7) << 4;

    for (int pt = 0; pt < PTILES; ++pt) {
        const int p0 = pt * MT;
        __syncthreads();
        {
            const int p = p0 + ar;
            const bool pv = (p < NP);
            const float* wp = Wm + (size_t)s * NK * NP + p;
            #pragma unroll
            for (int kk = 0; kk < 32; kk += 8) {
                const int kb = akc * 32 + kk;
                float v[8];
                #pragma unroll
                for (int j = 0; j < 8; ++j) {
                    const int k = kb + j;
                    v[j] = (pv && (k < NK)) ? wp[(size_t)k * NP] : 0.f;
                }
                u32x4 u;
                u.x = pack2bf(v[0], v[1]); u.y = pack2bf(v[2], v[3]);
                u.z = pack2bf(v[4], v[5]); u.w = pack2bf(v[6], v[7]);
                *(u32x4*)(As + ((ar * ROWB + kb * 2) ^ ars)) = u;
            }
        }
        __syncthreads();

        f32x4 acc[2][4];
        #pragma unroll
        for (int mi = 0; mi < 2; ++mi)
            #pragma unroll
            for (int ni = 0; ni < 4; ++ni)
                acc[mi][ni] = (f32x4){0.f, 0.f, 0.f, 0.f};

        #pragma unroll
        for (int kk = 0; kk < 3; ++kk) {
            const int kbyte = kk * 64 + lg * 16;
            bf16x8 bxyz[2], ap[4];
            #pragma unroll
            for (int mi = 0; mi < 2; ++mi) {
                const int row = w * 32 + mi * 16 + lr;
                bxyz[mi] = *(const bf16x8*)(Bs + ((row * ROWB + kbyte) ^ ls));
            }
            #pragma unroll
            for (int ni = 0; ni < 4; ++ni) {
                const int row = ni * 16 + lr;
                ap[ni] = *(const bf16x8*)(As + ((row * ROWB + kbyte) ^ ls));
            }
            #pragma unroll
            for (int mi = 0; mi < 2; ++mi)
                #pragma unroll
                for (int ni = 0; ni < 4; ++ni)
                    acc[mi][ni] = __builtin_amdgcn_mfma_f32_16x16x32_bf16(
                        bxyz[mi], ap[ni], acc[mi][ni], 0, 0, 0);
        }

        #pragma unroll
        for (int ni = 0; ni < 4; ++ni) {
            const int p = p0 + ni * 16 + lr;
            if (p < NP) {
                float* dst = ybase + (size_t)p * NXYZ + xyzbase;
                *(f32x4*)dst = acc[0][ni];
                *(f32x4*)(dst + 16) = acc[1][ni];
            }
        }
    }
}

extern "C" void kernel_launch(void* const* d_in, const int* in_sizes, int n_in,
                              void* d_out, int out_size, void* d_ws, size_t ws_size,
                              hipStream_t stream) {
    (void)in_sizes; (void)n_in; (void)out_size;
    const float* x  = (const float*)d_in[0];
    const float* Wm = (const float*)d_in[1];
    float* y = (float*)d_out;

    const size_t ws_need = (size_t)(XT_TASKS + WT_TASKS) * 1024;  // ~21.8 MB
    if (ws_size >= ws_need) {
        prep_frag<<<(XT_TASKS + WT_TASKS) / 4, 256, 0, stream>>>(x, Wm, (uint32_t*)d_ws);
        gemm_t<<<64 * NSEG * PTILES, 256, 0, stream>>>((const uint32_t*)d_ws, y);
    } else {
        interp_fallback<<<NB * NS * NF * NTILES, 192, 0, stream>>>(x, Wm, y);
    }
}

// Round 10
// 88.717 us; speedup vs baseline: 1.0065x; 1.0065x over previous
//
#include <hip/hip_runtime.h>
#include <cstdint>
#include <cstddef>

// Problem constants
#define NB 2
#define NF 8
#define NS 4
#define NK 90      // real K (dirs per shell)
#define NP 642     // grid vertices
#define NXYZ 1728  // 12*12*12
#define MT 64      // p-tile
#define PTILES 11  // ceil(642/64)
#define NG 108     // xyz 16-groups (1728/16)
#define XT_TASKS (64 * NG * 3)          // 20736 x-fragment blocks (1 KB each)
#define WT_TASKS (NS * PTILES * 4 * 3)  // 528 W-fragment blocks
#define GEMM_TASKS (64 * 54 * PTILES)   // 38016 wave tasks
#define XPREP_BLOCKS (64 * 9)           // 576 (e, 192-xyz segment)
#define WPREP_BLOCKS (WT_TASKS / 4)     // 132

typedef __attribute__((ext_vector_type(8))) __bf16 bf16x8;
typedef __attribute__((ext_vector_type(4))) float f32x4;
typedef __attribute__((ext_vector_type(4))) uint32_t u32x4;

// RNE pack of two f32 -> u32 holding 2 bf16
__device__ __forceinline__ uint32_t pack2bf(float a, float b) {
    uint32_t ua = __builtin_bit_cast(uint32_t, a);
    uint32_t ub = __builtin_bit_cast(uint32_t, b);
    ua += 0x7FFFu + ((ua >> 16) & 1u);
    ub += 0x7FFFu + ((ub >> 16) & 1u);
    return (ua >> 16) | (ub & 0xFFFF0000u);
}

// ============ Kernel 1: pack x and W into MFMA-fragment-order bf16 blocks,
// now with COALESCED x reads via LDS transpose (old prep read x with scalar
// stride-6912B dwords: 50% line utilization + poor MLP — suspected fat).
// ws layout identical to R5: x frag (e,g,kk) at ((e*108+g)*3+kk) KB,
//                            W frag at XT + ((s*11+pt)*4+ni)*3+kk KB.
__global__ __launch_bounds__(256) void prep_frag2(
    const float* __restrict__ x, const float* __restrict__ Wm,
    uint32_t* __restrict__ ws)
{
    const int tid  = (int)threadIdx.x;
    const int lane = tid & 63;
    const int w    = tid >> 6;
    const int lr = lane & 15, lg = lane >> 4;

    if ((int)blockIdx.x < XPREP_BLOCKS) {
        // ---- x part: block = (e, seg). LDS tile [96 k][192 xyz] bf16,
        // swizzle ^(((k>>3)&3)<<5) -> phase-2 column reads hit all 32 banks.
        __shared__ __align__(16) char lds[96 * 384];  // 36 KB
        const int e   = (int)blockIdx.x / 9;
        const int seg = (int)blockIdx.x % 9;
        const float* xe = x + (size_t)e * (NK * NXYZ) + seg * 192;

        // zero-fill pad rows k = 90..95
        for (int i = tid; i < 6 * 48; i += 256) {
            const int r = 90 + i / 48, c4 = i % 48;
            *(uint64_t*)(lds + ((r * 384 + c4 * 8) ^ (((r >> 3) & 3) << 5))) = 0ull;
        }
        // phase 1: coalesced f32x4 reads (768B runs per row), pack, LDS write
        #pragma unroll
        for (int pass = 0; pass < 17; ++pass) {
            const int i = tid + pass * 256;
            if (i < 90 * 48) {
                const int r = i / 48, c4 = i - r * 48;
                const f32x4 v = *(const f32x4*)(xe + (size_t)r * NXYZ + c4 * 4);
                const uint64_t uu = (uint64_t)pack2bf(v.x, v.y)
                                  | ((uint64_t)pack2bf(v.z, v.w) << 32);
                *(uint64_t*)(lds + ((r * 384 + c4 * 8) ^ (((r >> 3) & 3) << 5))) = uu;
            }
        }
        __syncthreads();
        // phase 2: emit 36 frag blocks (12 g x 3 kk); wave w -> 9 frags.
        #pragma unroll
        for (int q = 0; q < 9; ++q) {
            const int fi  = w * 9 + q;
            const int g_l = fi / 3, kk = fi % 3;
            const int c   = g_l * 16 + lr;
            uint32_t h[8];
            #pragma unroll
            for (int j = 0; j < 8; ++j) {
                const int k = kk * 32 + lg * 8 + j;
                h[j] = *(const uint16_t*)(
                    lds + ((k * 384 + c * 2) ^ (((k >> 3) & 3) << 5)));
            }
            u32x4 u;
            u.x = h[0] | (h[1] << 16);
            u.y = h[2] | (h[3] << 16);
            u.z = h[4] | (h[5] << 16);
            u.w = h[6] | (h[7] << 16);
            const int g = seg * 12 + g_l;
            *(u32x4*)((char*)ws + ((size_t)((e * NG + g) * 3 + kk)) * 1024
                      + lane * 16) = u;
        }
    } else {
        // ---- W part (0.5 MB total — scalar strided reads are fine)
        const int task = ((int)blockIdx.x - XPREP_BLOCKS) * 4 + w;
        int t = task;
        const int kk = t % 3;      t /= 3;
        const int ni = t % 4;      t /= 4;
        const int pt = t % PTILES; t /= PTILES;
        const int s  = t;                  // 0..3
        const int p = pt * MT + ni * 16 + lr;
        const float* src = Wm + (size_t)s * (NK * NP) + p;
        float v[8];
        #pragma unroll
        for (int j = 0; j < 8; ++j) {
            const int k = kk * 32 + lg * 8 + j;
            v[j] = (k < NK && p < NP) ? src[(size_t)k * NP] : 0.f;
        }
        u32x4 u;
        u.x = pack2bf(v[0], v[1]);
        u.y = pack2bf(v[2], v[3]);
        u.z = pack2bf(v[4], v[5]);
        u.w = pack2bf(v[6], v[7]);
        *(u32x4*)((char*)ws + (size_t)(XT_TASKS + task) * 1024 + lane * 16) = u;
    }
}

// ============ Kernel 2: barrier-free, LDS-free GEMM — UNCHANGED R5/R7
// structure (proven 82 µs; plain stores).
__global__ __launch_bounds__(256, 4) void gemm_frag(
    const uint32_t* __restrict__ ws, float* __restrict__ y)
{
    const int tid  = (int)threadIdx.x;
    const int lane = tid & 63;
    const int lr = lane & 15, lg = lane >> 4;
    int t = (int)blockIdx.x * 4 + (tid >> 6);
    const int pt  = t % PTILES; t /= PTILES;   // pt fastest: 4 waves of a block
    const int n32 = t % 54;     t /= 54;       // share the same B-frags (L1 hit)
    const int e   = t;                          // 0..63
    const int s = e & 3, bf = e >> 2;

    const char* base  = (const char*)ws + (size_t)lane * 16;
    const char* xbase = base + (size_t)((e * NG + n32 * 2) * 3) * 1024;
    const char* abase = base + (size_t)(XT_TASKS + ((s * PTILES + pt) * 4) * 3) * 1024;

    bf16x8 bfr[2][3], afr[4][3];
    #pragma unroll
    for (int mi = 0; mi < 2; ++mi)
        #pragma unroll
        for (int kk = 0; kk < 3; ++kk)
            bfr[mi][kk] = *(const bf16x8*)(xbase + (mi * 3 + kk) * 1024);
    #pragma unroll
    for (int ni = 0; ni < 4; ++ni)
        #pragma unroll
        for (int kk = 0; kk < 3; ++kk)
            afr[ni][kk] = *(const bf16x8*)(abase + (ni * 3 + kk) * 1024);

    f32x4 acc[2][4];
    #pragma unroll
    for (int mi = 0; mi < 2; ++mi)
        #pragma unroll
        for (int ni = 0; ni < 4; ++ni)
            acc[mi][ni] = (f32x4){0.f, 0.f, 0.f, 0.f};

    #pragma unroll
    for (int kk = 0; kk < 3; ++kk)
        #pragma unroll
        for (int mi = 0; mi < 2; ++mi)
            #pragma unroll
            for (int ni = 0; ni < 4; ++ni)
                acc[mi][ni] = __builtin_amdgcn_mfma_f32_16x16x32_bf16(
                    bfr[mi][kk], afr[ni][kk], acc[mi][ni], 0, 0, 0);

    const int b = bf >> 3, f = bf & 7;
    const size_t chan = (size_t)b * (NS * NF) + (size_t)s * NF + f;
    float* ybase = y + chan * ((size_t)NP * NXYZ) + n32 * 32 + lg * 4;
    #pragma unroll
    for (int ni = 0; ni < 4; ++ni) {
        const int p = pt * MT + ni * 16 + lr;
        if (p < NP) {
            float* dst = ybase + (size_t)p * NXYZ;
            *(f32x4*)dst = acc[0][ni];
            *(f32x4*)(dst + 16) = acc[1][ni];
        }
    }
}

// ============ Fallback (round-3 structure) if ws too small ================
#define NT 96
#define NTILES 18
#define KP 96
#define ROWB (KP * 2)

__global__ __launch_bounds__(192, 4) void interp_fallback(
    const float* __restrict__ x, const float* __restrict__ Wm,
    float* __restrict__ y)
{
    __shared__ __align__(16) char As[MT * ROWB];
    __shared__ __align__(16) char Bs[NT * ROWB];

    int blk = (int)blockIdx.x;
    const int nt = blk % NTILES; blk /= NTILES;
    const int f  = blk % NF;     blk /= NF;
    const int s  = blk % NS;     blk /= NS;
    const int b  = blk;
    const int tid = (int)threadIdx.x;
    const int n0 = nt * NT;

    {
        const int c  = tid % NT;
        const int kh = tid / NT;
        const float* xp = x + (((size_t)b * NF + f) * (NS * NK) + (size_t)s * NK) * NXYZ
                            + n0 + c;
        const int cs = (c & 7) << 4;
        #pragma unroll
        for (int kk = 0; kk < 48; kk += 8) {
            const int kb = kh * 48 + kk;
            float v[8];
            #pragma unroll
            for (int j = 0; j < 8; ++j) {
                const int k = kb + j;
                v[j] = (k < NK) ? xp[(size_t)k * NXYZ] : 0.f;
            }
            u32x4 u;
            u.x = pack2bf(v[0], v[1]); u.y = pack2bf(v[2], v[3]);
            u.z = pack2bf(v[4], v[5]); u.w = pack2bf(v[6], v[7]);
            *(u32x4*)(Bs + ((c * ROWB + kb * 2) ^ cs)) = u;
        }
    }

    const int lane = tid & 63;
    const int w  = tid / 64;
    const int lr = lane & 15;
    const int lg = lane >> 4;
    const int ls = (lr & 7) << 4;
    const size_t chan = (size_t)b * (NS * NF) + (size_t)s * NF + f;
    float* ybase = y + chan * ((size_t)NP * NXYZ);
    const int xyzbase = n0 + w * 32 + lg * 4;
    const int ar = tid & 63;
    const int akc = tid >> 6;
    const int ars = (ar & 7) << 4;

    for (int pt = 0; pt < PTILES; ++pt) {
        const int p0 = pt * MT;
        __syncthreads();
        {
            const int p = p0 + ar;
            const bool pv = (p < NP);
            const float* wp = Wm + (size_t)s * NK * NP + p;
            #pragma unroll
            for (int kk = 0; kk < 32; kk += 8) {
                const int kb = akc * 32 + kk;
                float v[8];
                #pragma unroll
                for (int j = 0; j < 8; ++j) {
                    const int k = kb + j;
                    v[j] = (pv && (k < NK)) ? wp[(size_t)k * NP] : 0.f;
                }
                u32x4 u;
                u.x = pack2bf(v[0], v[1]); u.y = pack2bf(v[2], v[3]);
                u.z = pack2bf(v[4], v[5]); u.w = pack2bf(v[6], v[7]);
                *(u32x4*)(As + ((ar * ROWB + kb * 2) ^ ars)) = u;
            }
        }
        __syncthreads();

        f32x4 acc[2][4];
        #pragma unroll
        for (int mi = 0; mi < 2; ++mi)
            #pragma unroll
            for (int ni = 0; ni < 4; ++ni)
                acc[mi][ni] = (f32x4){0.f, 0.f, 0.f, 0.f};

        #pragma unroll
        for (int kk = 0; kk < 3; ++kk) {
            const int kbyte = kk * 64 + lg * 16;
            bf16x8 bxyz[2], ap[4];
            #pragma unroll
            for (int mi = 0; mi < 2; ++mi) {
                const int row = w * 32 + mi * 16 + lr;
                bxyz[mi] = *(const bf16x8*)(Bs + ((row * ROWB + kbyte) ^ ls));
            }
            #pragma unroll
            for (int ni = 0; ni < 4; ++ni) {
                const int row = ni * 16 + lr;
                ap[ni] = *(const bf16x8*)(As + ((row * ROWB + kbyte) ^ ls));
            }
            #pragma unroll
            for (int mi = 0; mi < 2; ++mi)
                #pragma unroll
                for (int ni = 0; ni < 4; ++ni)
                    acc[mi][ni] = __builtin_amdgcn_mfma_f32_16x16x32_bf16(
                        bxyz[mi], ap[ni], acc[mi][ni], 0, 0, 0);
        }

        #pragma unroll
        for (int ni = 0; ni < 4; ++ni) {
            const int p = p0 + ni * 16 + lr;
            if (p < NP) {
                float* dst = ybase + (size_t)p * NXYZ + xyzbase;
                *(f32x4*)dst = acc[0][ni];
                *(f32x4*)(dst + 16) = acc[1][ni];
            }
        }
    }
}

extern "C" void kernel_launch(void* const* d_in, const int* in_sizes, int n_in,
                              void* d_out, int out_size, void* d_ws, size_t ws_size,
                              hipStream_t stream) {
    (void)in_sizes; (void)n_in; (void)out_size;
    const float* x  = (const float*)d_in[0];
    const float* Wm = (const float*)d_in[1];
    float* y = (float*)d_out;

    const size_t ws_need = (size_t)(XT_TASKS + WT_TASKS) * 1024;  // ~21.8 MB
    if (ws_size >= ws_need) {
        prep_frag2<<<XPREP_BLOCKS + WPREP_BLOCKS, 256, 0, stream>>>(
            x, Wm, (uint32_t*)d_ws);
        gemm_frag<<<GEMM_TASKS / 4, 256, 0, stream>>>((const uint32_t*)d_ws, y);
    } else {
        interp_fallback<<<NB * NS * NF * NTILES, 192, 0, stream>>>(x, Wm, y);
    }
}

// Round 11
// 80.898 us; speedup vs baseline: 1.1037x; 1.0967x over previous
//
#include <hip/hip_runtime.h>
#include <cstdint>
#include <cstddef>

// Problem constants
#define NB 2
#define NF 8
#define NS 4
#define NK 90      // real K (dirs per shell)
#define NP 642     // grid vertices
#define NXYZ 1728  // 12*12*12
#define MT 64      // p-tile
#define PTILES 11  // ceil(642/64)
#define NG 108     // xyz 16-groups (1728/16)
#define XT_TASKS (64 * NG * 3)          // 20736 x-fragment blocks (1 KB each)
#define WT_TASKS (NS * PTILES * 4 * 3)  // 528 W-fragment blocks
#define GEMM_TASKS (64 * 54 * PTILES)   // 38016 wave tasks
#define GEMM_BLOCKS (GEMM_TASKS / 4)    // 9504 = 8 * 1188 (exact -> bijective swizzle)
#define NXCD 8
#define CPX (GEMM_BLOCKS / NXCD)        // 1188 blocks per XCD chunk

typedef __attribute__((ext_vector_type(8))) __bf16 bf16x8;
typedef __attribute__((ext_vector_type(4))) float f32x4;
typedef __attribute__((ext_vector_type(4))) uint32_t u32x4;

// RNE pack of two f32 -> u32 holding 2 bf16
__device__ __forceinline__ uint32_t pack2bf(float a, float b) {
    uint32_t ua = __builtin_bit_cast(uint32_t, a);
    uint32_t ub = __builtin_bit_cast(uint32_t, b);
    ua += 0x7FFFu + ((ua >> 16) & 1u);
    ub += 0x7FFFu + ((ub >> 16) & 1u);
    return (ua >> 16) | (ub & 0xFFFF0000u);
}

// ============ Kernel 1: pack x and W into MFMA-fragment-order bf16 blocks.
// (R5 structure — fastest prep measured; R10's LDS-transpose variant was
// slower. Scalar strided reads, coalesced 16-lane runs.)
__global__ __launch_bounds__(256) void prep_frag(
    const float* __restrict__ x, const float* __restrict__ Wm,
    uint32_t* __restrict__ ws)
{
    const int tid  = (int)threadIdx.x;
    const int lane = tid & 63;
    const int lr = lane & 15, lg = lane >> 4;
    const int task = (int)blockIdx.x * 4 + (tid >> 6);

    float v[8];
    if (task < XT_TASKS) {
        int t = task;
        const int kk = t % 3;   t /= 3;
        const int g  = t % NG;  t /= NG;
        const int e  = t;                  // 0..63
        const int s = e & 3, bf = e >> 2;
        const float* src = x + (size_t)bf * (NS * NK * NXYZ)
                             + (size_t)s * (NK * NXYZ) + g * 16 + lr;
        #pragma unroll
        for (int j = 0; j < 8; ++j) {
            const int k = kk * 32 + lg * 8 + j;
            v[j] = (k < NK) ? src[(size_t)k * NXYZ] : 0.f;
        }
    } else {
        int t = task - XT_TASKS;
        const int kk = t % 3;      t /= 3;
        const int ni = t % 4;      t /= 4;
        const int pt = t % PTILES; t /= PTILES;
        const int s  = t;                  // 0..3
        const int p = pt * MT + ni * 16 + lr;
        const float* src = Wm + (size_t)s * (NK * NP) + p;
        #pragma unroll
        for (int j = 0; j < 8; ++j) {
            const int k = kk * 32 + lg * 8 + j;
            v[j] = (k < NK && p < NP) ? src[(size_t)k * NP] : 0.f;
        }
    }
    u32x4 u;
    u.x = pack2bf(v[0], v[1]);
    u.y = pack2bf(v[2], v[3]);
    u.z = pack2bf(v[4], v[5]);
    u.w = pack2bf(v[6], v[7]);
    *(u32x4*)((char*)ws + (size_t)task * 1024 + lane * 16) = u;
}

// ============ Kernel 2: barrier-free, LDS-free GEMM (R7 winner) + T1
// XCD-aware bijective block swizzle. HW assigns block i -> XCD i%8;
// remap orig = (i%8)*CPX + i/8 so each XCD owns 1188 CONSECUTIVE original
// blocks: (e,n32) fragment groups re-read within ONE XCD's L2 (not 8x via
// L3), and each XCD's write stream covers a contiguous ~35 MB y-region.
__global__ __launch_bounds__(256, 4) void gemm_frag(
    const uint32_t* __restrict__ ws, float* __restrict__ y)
{
    const int tid  = (int)threadIdx.x;
    const int lane = tid & 63;
    const int lr = lane & 15, lg = lane >> 4;

    const int i = (int)blockIdx.x;
    const int orig = (i % NXCD) * CPX + i / NXCD;   // bijective: 9504 = 8*1188
    int t = orig * 4 + (tid >> 6);
    const int pt  = t % PTILES; t /= PTILES;   // pt fastest: sibling waves/blocks
    const int n32 = t % 54;     t /= 54;       // share the same B-frags
    const int e   = t;                          // 0..63
    const int s = e & 3, bf = e >> 2;

    const char* base  = (const char*)ws + (size_t)lane * 16;
    const char* xbase = base + (size_t)((e * NG + n32 * 2) * 3) * 1024;
    const char* abase = base + (size_t)(XT_TASKS + ((s * PTILES + pt) * 4) * 3) * 1024;

    bf16x8 bfr[2][3], afr[4][3];
    #pragma unroll
    for (int mi = 0; mi < 2; ++mi)
        #pragma unroll
        for (int kk = 0; kk < 3; ++kk)
            bfr[mi][kk] = *(const bf16x8*)(xbase + (mi * 3 + kk) * 1024);
    #pragma unroll
    for (int ni = 0; ni < 4; ++ni)
        #pragma unroll
        for (int kk = 0; kk < 3; ++kk)
            afr[ni][kk] = *(const bf16x8*)(abase + (ni * 3 + kk) * 1024);

    f32x4 acc[2][4];
    #pragma unroll
    for (int mi = 0; mi < 2; ++mi)
        #pragma unroll
        for (int ni = 0; ni < 4; ++ni)
            acc[mi][ni] = (f32x4){0.f, 0.f, 0.f, 0.f};

    #pragma unroll
    for (int kk = 0; kk < 3; ++kk)
        #pragma unroll
        for (int mi = 0; mi < 2; ++mi)
            #pragma unroll
            for (int ni = 0; ni < 4; ++ni)
                acc[mi][ni] = __builtin_amdgcn_mfma_f32_16x16x32_bf16(
                    bfr[mi][kk], afr[ni][kk], acc[mi][ni], 0, 0, 0);

    const int b = bf >> 3, f = bf & 7;
    const size_t chan = (size_t)b * (NS * NF) + (size_t)s * NF + f;
    float* ybase = y + chan * ((size_t)NP * NXYZ) + n32 * 32 + lg * 4;
    #pragma unroll
    for (int ni = 0; ni < 4; ++ni) {
        const int p = pt * MT + ni * 16 + lr;
        if (p < NP) {
            float* dst = ybase + (size_t)p * NXYZ;
            *(f32x4*)dst = acc[0][ni];
            *(f32x4*)(dst + 16) = acc[1][ni];
        }
    }
}

// ============ Fallback (round-3 structure) if ws too small ================
#define NT 96
#define NTILES 18
#define KP 96
#define ROWB (KP * 2)

__global__ __launch_bounds__(192, 4) void interp_fallback(
    const float* __restrict__ x, const float* __restrict__ Wm,
    float* __restrict__ y)
{
    __shared__ __align__(16) char As[MT * ROWB];
    __shared__ __align__(16) char Bs[NT * ROWB];

    int blk = (int)blockIdx.x;
    const int nt = blk % NTILES; blk /= NTILES;
    const int f  = blk % NF;     blk /= NF;
    const int s  = blk % NS;     blk /= NS;
    const int b  = blk;
    const int tid = (int)threadIdx.x;
    const int n0 = nt * NT;

    {
        const int c  = tid % NT;
        const int kh = tid / NT;
        const float* xp = x + (((size_t)b * NF + f) * (NS * NK) + (size_t)s * NK) * NXYZ
                            + n0 + c;
        const int cs = (c & 7) << 4;
        #pragma unroll
        for (int kk = 0; kk < 48; kk += 8) {
            const int kb = kh * 48 + kk;
            float v[8];
            #pragma unroll
            for (int j = 0; j < 8; ++j) {
                const int k = kb + j;
                v[j] = (k < NK) ? xp[(size_t)k * NXYZ] : 0.f;
            }
            u32x4 u;
            u.x = pack2bf(v[0], v[1]); u.y = pack2bf(v[2], v[3]);
            u.z = pack2bf(v[4], v[5]); u.w = pack2bf(v[6], v[7]);
            *(u32x4*)(Bs + ((c * ROWB + kb * 2) ^ cs)) = u;
        }
    }

    const int lane = tid & 63;
    const int w  = tid / 64;
    const int lr = lane & 15;
    const int lg = lane >> 4;
    const int ls = (lr & 7) << 4;
    const size_t chan = (size_t)b * (NS * NF) + (size_t)s * NF + f;
    float* ybase = y + chan * ((size_t)NP * NXYZ);
    const int xyzbase = n0 + w * 32 + lg * 4;
    const int ar = tid & 63;
    const int akc = tid >> 6;
    const int ars = (ar & 7) << 4;

    for (int pt = 0; pt < PTILES; ++pt) {
        const int p0 = pt * MT;
        __syncthreads();
        {
            const int p = p0 + ar;
            const bool pv = (p < NP);
            const float* wp = Wm + (size_t)s * NK * NP + p;
            #pragma unroll
            for (int kk = 0; kk < 32; kk += 8) {
                const int kb = akc * 32 + kk;
                float v[8];
                #pragma unroll
                for (int j = 0; j < 8; ++j) {
                    const int k = kb + j;
                    v[j] = (pv && (k < NK)) ? wp[(size_t)k * NP] : 0.f;
                }
                u32x4 u;
                u.x = pack2bf(v[0], v[1]); u.y = pack2bf(v[2], v[3]);
                u.z = pack2bf(v[4], v[5]); u.w = pack2bf(v[6], v[7]);
                *(u32x4*)(As + ((ar * ROWB + kb * 2) ^ ars)) = u;
            }
        }
        __syncthreads();

        f32x4 acc[2][4];
        #pragma unroll
        for (int mi = 0; mi < 2; ++mi)
            #pragma unroll
            for (int ni = 0; ni < 4; ++ni)
                acc[mi][ni] = (f32x4){0.f, 0.f, 0.f, 0.f};

        #pragma unroll
        for (int kk = 0; kk < 3; ++kk) {
            const int kbyte = kk * 64 + lg * 16;
            bf16x8 bxyz[2], ap[4];
            #pragma unroll
            for (int mi = 0; mi < 2; ++mi) {
                const int row = w * 32 + mi * 16 + lr;
                bxyz[mi] = *(const bf16x8*)(Bs + ((row * ROWB + kbyte) ^ ls));
            }
            #pragma unroll
            for (int ni = 0; ni < 4; ++ni) {
                const int row = ni * 16 + lr;
                ap[ni] = *(const bf16x8*)(As + ((row * ROWB + kbyte) ^ ls));
            }
            #pragma unroll
            for (int mi = 0; mi < 2; ++mi)
                #pragma unroll
                for (int ni = 0; ni < 4; ++ni)
                    acc[mi][ni] = __builtin_amdgcn_mfma_f32_16x16x32_bf16(
                        bxyz[mi], ap[ni], acc[mi][ni], 0, 0, 0);
        }

        #pragma unroll
        for (int ni = 0; ni < 4; ++ni) {
            const int p = p0 + ni * 16 + lr;
            if (p < NP) {
                float* dst = ybase + (size_t)p * NXYZ + xyzbase;
                *(f32x4*)dst = acc[0][ni];
                *(f32x4*)(dst + 16) = acc[1][ni];
            }
        }
    }
}

extern "C" void kernel_launch(void* const* d_in, const int* in_sizes, int n_in,
                              void* d_out, int out_size, void* d_ws, size_t ws_size,
                              hipStream_t stream) {
    (void)in_sizes; (void)n_in; (void)out_size;
    const float* x  = (const float*)d_in[0];
    const float* Wm = (const float*)d_in[1];
    float* y = (float*)d_out;

    const size_t ws_need = (size_t)(XT_TASKS + WT_TASKS) * 1024;  // ~21.8 MB
    if (ws_size >= ws_need) {
        prep_frag<<<(XT_TASKS + WT_TASKS) / 4, 256, 0, stream>>>(x, Wm, (uint32_t*)d_ws);
        gemm_frag<<<GEMM_BLOCKS, 256, 0, stream>>>((const uint32_t*)d_ws, y);
    } else {
        interp_fallback<<<NB * NS * NF * NTILES, 192, 0, stream>>>(x, Wm, y);
    }
}

// Round 12
// 76.313 us; speedup vs baseline: 1.1701x; 1.0601x over previous
//
#include <hip/hip_runtime.h>
#include <cstdint>
#include <cstddef>

// Problem constants
#define NB 2
#define NF 8
#define NS 4
#define NK 90      // real K (dirs per shell)
#define NP 642     // grid vertices
#define NXYZ 1728  // 12*12*12
#define MT 64      // p-tile
#define PTILES 11  // ceil(642/64)
#define NG 108     // xyz 16-groups (1728/16)
#define XT_TASKS (64 * NG * 3)          // 20736 x-fragment blocks (1 KB each)
#define WT_TASKS (NS * PTILES * 4 * 3)  // 528 W-fragment blocks
#define NPAIR 27                        // n32-pairs (54/2)
#define GEMM_TASKS (64 * NPAIR * PTILES)  // 19008 wave tasks
#define GEMM_BLOCKS (GEMM_TASKS / 4)      // 4752 = 8 * 594 (exact -> bijective)
#define NXCD 8
#define CPX (GEMM_BLOCKS / NXCD)          // 594

typedef __attribute__((ext_vector_type(8))) __bf16 bf16x8;
typedef __attribute__((ext_vector_type(4))) float f32x4;
typedef __attribute__((ext_vector_type(4))) uint32_t u32x4;

// RNE pack of two f32 -> u32 holding 2 bf16
__device__ __forceinline__ uint32_t pack2bf(float a, float b) {
    uint32_t ua = __builtin_bit_cast(uint32_t, a);
    uint32_t ub = __builtin_bit_cast(uint32_t, b);
    ua += 0x7FFFu + ((ua >> 16) & 1u);
    ub += 0x7FFFu + ((ub >> 16) & 1u);
    return (ua >> 16) | (ub & 0xFFFF0000u);
}

// ============ Kernel 1: pack x and W into MFMA-fragment-order bf16 blocks.
// (R5 structure — fastest prep measured.)
__global__ __launch_bounds__(256) void prep_frag(
    const float* __restrict__ x, const float* __restrict__ Wm,
    uint32_t* __restrict__ ws)
{
    const int tid  = (int)threadIdx.x;
    const int lane = tid & 63;
    const int lr = lane & 15, lg = lane >> 4;
    const int task = (int)blockIdx.x * 4 + (tid >> 6);

    float v[8];
    if (task < XT_TASKS) {
        int t = task;
        const int kk = t % 3;   t /= 3;
        const int g  = t % NG;  t /= NG;
        const int e  = t;                  // 0..63
        const int s = e & 3, bf = e >> 2;
        const float* src = x + (size_t)bf * (NS * NK * NXYZ)
                             + (size_t)s * (NK * NXYZ) + g * 16 + lr;
        #pragma unroll
        for (int j = 0; j < 8; ++j) {
            const int k = kk * 32 + lg * 8 + j;
            v[j] = (k < NK) ? src[(size_t)k * NXYZ] : 0.f;
        }
    } else {
        int t = task - XT_TASKS;
        const int kk = t % 3;      t /= 3;
        const int ni = t % 4;      t /= 4;
        const int pt = t % PTILES; t /= PTILES;
        const int s  = t;                  // 0..3
        const int p = pt * MT + ni * 16 + lr;
        const float* src = Wm + (size_t)s * (NK * NP) + p;
        #pragma unroll
        for (int j = 0; j < 8; ++j) {
            const int k = kk * 32 + lg * 8 + j;
            v[j] = (k < NK && p < NP) ? src[(size_t)k * NP] : 0.f;
        }
    }
    u32x4 u;
    u.x = pack2bf(v[0], v[1]);
    u.y = pack2bf(v[2], v[3]);
    u.z = pack2bf(v[4], v[5]);
    u.w = pack2bf(v[6], v[7]);
    *(u32x4*)((char*)ws + (size_t)task * 1024 + lane * 16) = u;
}

// ============ Kernel 2: barrier-free GEMM, 2 n32-groups per wave.
// A-frags depend on (s,pt) only -> reused for both halves: 24 loads feed
// 48 MFMA + 16 stores (was 18:24:8). Wave count halves (19008), A-frag L2
// traffic halves. All loads issued up front; acc reused across halves.
// T1 bijective XCD swizzle kept (4752 = 8*594).
__global__ __launch_bounds__(256, 3) void gemm_frag2(
    const uint32_t* __restrict__ ws, float* __restrict__ y)
{
    const int tid  = (int)threadIdx.x;
    const int lane = tid & 63;
    const int lr = lane & 15, lg = lane >> 4;

    const int i = (int)blockIdx.x;
    const int orig = (i % NXCD) * CPX + i / NXCD;   // bijective
    int t = orig * 4 + (tid >> 6);
    const int pt = t % PTILES; t /= PTILES;   // pt fastest within block
    const int pr = t % NPAIR;  t /= NPAIR;    // n32-pair: n32 = 2*pr, 2*pr+1
    const int e  = t;                          // 0..63
    const int s = e & 3, bf = e >> 2;

    const char* base  = (const char*)ws + (size_t)lane * 16;
    // B-frags: 4 16-groups (g = pr*4 .. pr*4+3) x 3 kk
    const char* xbase = base + (size_t)((e * NG + pr * 4) * 3) * 1024;
    const char* abase = base + (size_t)(XT_TASKS + ((s * PTILES + pt) * 4) * 3) * 1024;

    bf16x8 bfr[4][3], afr[4][3];
    #pragma unroll
    for (int gi = 0; gi < 4; ++gi)
        #pragma unroll
        for (int kk = 0; kk < 3; ++kk)
            bfr[gi][kk] = *(const bf16x8*)(xbase + (gi * 3 + kk) * 1024);
    #pragma unroll
    for (int ni = 0; ni < 4; ++ni)
        #pragma unroll
        for (int kk = 0; kk < 3; ++kk)
            afr[ni][kk] = *(const bf16x8*)(abase + (ni * 3 + kk) * 1024);

    const int b = bf >> 3, f = bf & 7;
    const size_t chan = (size_t)b * (NS * NF) + (size_t)s * NF + f;
    float* ybase = y + chan * ((size_t)NP * NXYZ) + pr * 64 + lg * 4;

    #pragma unroll
    for (int h = 0; h < 2; ++h) {       // two n32 halves, acc/regs reused
        f32x4 acc[2][4];
        #pragma unroll
        for (int mi = 0; mi < 2; ++mi)
            #pragma unroll
            for (int ni = 0; ni < 4; ++ni)
                acc[mi][ni] = (f32x4){0.f, 0.f, 0.f, 0.f};

        #pragma unroll
        for (int kk = 0; kk < 3; ++kk)
            #pragma unroll
            for (int mi = 0; mi < 2; ++mi)
                #pragma unroll
                for (int ni = 0; ni < 4; ++ni)
                    acc[mi][ni] = __builtin_amdgcn_mfma_f32_16x16x32_bf16(
                        bfr[h * 2 + mi][kk], afr[ni][kk], acc[mi][ni], 0, 0, 0);

        float* yh = ybase + h * 32;
        #pragma unroll
        for (int ni = 0; ni < 4; ++ni) {
            const int p = pt * MT + ni * 16 + lr;
            if (p < NP) {
                float* dst = yh + (size_t)p * NXYZ;
                *(f32x4*)dst = acc[0][ni];
                *(f32x4*)(dst + 16) = acc[1][ni];
            }
        }
    }
}

// ============ Fallback (round-3 structure) if ws too small ================
#define NT 96
#define NTILES 18
#define KP 96
#define ROWB (KP * 2)

__global__ __launch_bounds__(192, 4) void interp_fallback(
    const float* __restrict__ x, const float* __restrict__ Wm,
    float* __restrict__ y)
{
    __shared__ __align__(16) char As[MT * ROWB];
    __shared__ __align__(16) char Bs[NT * ROWB];

    int blk = (int)blockIdx.x;
    const int nt = blk % NTILES; blk /= NTILES;
    const int f  = blk % NF;     blk /= NF;
    const int s  = blk % NS;     blk /= NS;
    const int b  = blk;
    const int tid = (int)threadIdx.x;
    const int n0 = nt * NT;

    {
        const int c  = tid % NT;
        const int kh = tid / NT;
        const float* xp = x + (((size_t)b * NF + f) * (NS * NK) + (size_t)s * NK) * NXYZ
                            + n0 + c;
        const int cs = (c & 7) << 4;
        #pragma unroll
        for (int kk = 0; kk < 48; kk += 8) {
            const int kb = kh * 48 + kk;
            float v[8];
            #pragma unroll
            for (int j = 0; j < 8; ++j) {
                const int k = kb + j;
                v[j] = (k < NK) ? xp[(size_t)k * NXYZ] : 0.f;
            }
            u32x4 u;
            u.x = pack2bf(v[0], v[1]); u.y = pack2bf(v[2], v[3]);
            u.z = pack2bf(v[4], v[5]); u.w = pack2bf(v[6], v[7]);
            *(u32x4*)(Bs + ((c * ROWB + kb * 2) ^ cs)) = u;
        }
    }

    const int lane = tid & 63;
    const int w  = tid / 64;
    const int lr = lane & 15;
    const int lg = lane >> 4;
    const int ls = (lr & 7) << 4;
    const size_t chan = (size_t)b * (NS * NF) + (size_t)s * NF + f;
    float* ybase = y + chan * ((size_t)NP * NXYZ);
    const int xyzbase = n0 + w * 32 + lg * 4;
    const int ar = tid & 63;
    const int akc = tid >> 6;
    const int ars = (ar & 7) << 4;

    for (int pt = 0; pt < PTILES; ++pt) {
        const int p0 = pt * MT;
        __syncthreads();
        {
            const int p = p0 + ar;
            const bool pv = (p < NP);
            const float* wp = Wm + (size_t)s * NK * NP + p;
            #pragma unroll
            for (int kk = 0; kk < 32; kk += 8) {
                const int kb = akc * 32 + kk;
                float v[8];
                #pragma unroll
                for (int j = 0; j < 8; ++j) {
                    const int k = kb + j;
                    v[j] = (pv && (k < NK)) ? wp[(size_t)k * NP] : 0.f;
                }
                u32x4 u;
                u.x = pack2bf(v[0], v[1]); u.y = pack2bf(v[2], v[3]);
                u.z = pack2bf(v[4], v[5]); u.w = pack2bf(v[6], v[7]);
                *(u32x4*)(As + ((ar * ROWB + kb * 2) ^ ars)) = u;
            }
        }
        __syncthreads();

        f32x4 acc[2][4];
        #pragma unroll
        for (int mi = 0; mi < 2; ++mi)
            #pragma unroll
            for (int ni = 0; ni < 4; ++ni)
                acc[mi][ni] = (f32x4){0.f, 0.f, 0.f, 0.f};

        #pragma unroll
        for (int kk = 0; kk < 3; ++kk) {
            const int kbyte = kk * 64 + lg * 16;
            bf16x8 bxyz[2], ap[4];
            #pragma unroll
            for (int mi = 0; mi < 2; ++mi) {
                const int row = w * 32 + mi * 16 + lr;
                bxyz[mi] = *(const bf16x8*)(Bs + ((row * ROWB + kbyte) ^ ls));
            }
            #pragma unroll
            for (int ni = 0; ni < 4; ++ni) {
                const int row = ni * 16 + lr;
                ap[ni] = *(const bf16x8*)(As + ((row * ROWB + kbyte) ^ ls));
            }
            #pragma unroll
            for (int mi = 0; mi < 2; ++mi)
                #pragma unroll
                for (int ni = 0; ni < 4; ++ni)
                    acc[mi][ni] = __builtin_amdgcn_mfma_f32_16x16x32_bf16(
                        bxyz[mi], ap[ni], acc[mi][ni], 0, 0, 0);
        }

        #pragma unroll
        for (int ni = 0; ni < 4; ++ni) {
            const int p = p0 + ni * 16 + lr;
            if (p < NP) {
                float* dst = ybase + (size_t)p * NXYZ + xyzbase;
                *(f32x4*)dst = acc[0][ni];
                *(f32x4*)(dst + 16) = acc[1][ni];
            }
        }
    }
}

extern "C" void kernel_launch(void* const* d_in, const int* in_sizes, int n_in,
                              void* d_out, int out_size, void* d_ws, size_t ws_size,
                              hipStream_t stream) {
    (void)in_sizes; (void)n_in; (void)out_size;
    const float* x  = (const float*)d_in[0];
    const float* Wm = (const float*)d_in[1];
    float* y = (float*)d_out;

    const size_t ws_need = (size_t)(XT_TASKS + WT_TASKS) * 1024;  // ~21.8 MB
    if (ws_size >= ws_need) {
        prep_frag<<<(XT_TASKS + WT_TASKS) / 4, 256, 0, stream>>>(x, Wm, (uint32_t*)d_ws);
        gemm_frag2<<<GEMM_BLOCKS, 256, 0, stream>>>((const uint32_t*)d_ws, y);
    } else {
        interp_fallback<<<NB * NS * NF * NTILES, 192, 0, stream>>>(x, Wm, y);
    }
}